// Round 5
// baseline (364.107 us; speedup 1.0000x reference)
//
#include <hip/hip_runtime.h>
#include <hip/hip_bf16.h>

// ---------------------------------------------------------------------------
// DiffAttention forward: x@Wq/Wk/Wv -> RoPE -> diff attn -> @Wo
// L=2048, DIM=2048, 16 heads x (2x64), KV 8 heads x (2x64), V dv=128, causal.
// lambda = 0.2, scale = 1/8.
// ---------------------------------------------------------------------------

typedef __bf16 bf16x8 __attribute__((ext_vector_type(8)));
typedef short  s16x8  __attribute__((ext_vector_type(8)));
typedef float  f32x4  __attribute__((ext_vector_type(4)));

#define D4 4096  // QKV buffer row width: [Q 2048 | K 1024 | V 1024]

__device__ __forceinline__ ushort f2bfu(float f) {
  __hip_bfloat16 h = __float2bfloat16(f);
  return __builtin_bit_cast(ushort, h);
}
__device__ __forceinline__ float bfu2f(ushort u) {
  return __bfloat162float(__builtin_bit_cast(__hip_bfloat16, u));
}
__device__ __forceinline__ void gload_lds16(const void* g, void* l) {
  __builtin_amdgcn_global_load_lds(
      (const __attribute__((address_space(1))) unsigned int*)g,
      (__attribute__((address_space(3))) unsigned int*)l, 16, 0, 0);
}
__device__ __forceinline__ f32x4 mfma16(bf16x8 a, bf16x8 b, f32x4 c) {
  return __builtin_amdgcn_mfma_f32_16x16x32_bf16(a, b, c, 0, 0, 0);
}

// ---------------- convert x (f32) -> bf16 ----------------
__global__ __launch_bounds__(256) void cvt_x_kernel(const float* __restrict__ x,
                                                    ushort* __restrict__ xb) {
  const int i = blockIdx.x * 256 + threadIdx.x;  // each handles 4 elems
  float4 v = ((const float4*)x)[i];
  ((ushort4*)xb)[i] = make_ushort4(f2bfu(v.x), f2bfu(v.y), f2bfu(v.z), f2bfu(v.w));
}

// ---------------- W [K][N] f32 -> WT [N][K] bf16 ----------------
__global__ __launch_bounds__(256) void transpose_bf16_kernel(const float* __restrict__ W,
                                                             ushort* __restrict__ WT,
                                                             int K, int N) {
  __shared__ float tile[32][33];
  const int bx = blockIdx.x, by = blockIdx.y;
  const int tx = threadIdx.x, ty = threadIdx.y;  // (32,8)
#pragma unroll
  for (int j = 0; j < 32; j += 8)
    tile[ty + j][tx] = W[(size_t)(by * 32 + ty + j) * N + bx * 32 + tx];
  __syncthreads();
#pragma unroll
  for (int j = 0; j < 32; j += 8)
    WT[(size_t)(bx * 32 + ty + j) * K + by * 32 + tx] = f2bfu(tile[tx][ty + j]);
}

// ---------------- V columns of QKV (bf16) -> VT[g*128+dv][l] (bf16) ----------------
__global__ __launch_bounds__(256) void vtrans_kernel(const ushort* __restrict__ QKV,
                                                     ushort* __restrict__ VT) {
  __shared__ ushort tile[32][34];
  const int bx = blockIdx.x, by = blockIdx.y;  // bx: l-tile (64), by: c-tile (32)
  const int tx = threadIdx.x, ty = threadIdx.y;  // (32,8)
#pragma unroll
  for (int j = 0; j < 32; j += 8)
    tile[ty + j][tx] = QKV[(size_t)(bx * 32 + ty + j) * D4 + 3072 + by * 32 + tx];
  __syncthreads();
#pragma unroll
  for (int j = 0; j < 32; j += 8)
    VT[(size_t)(by * 32 + ty + j) * 2048 + bx * 32 + tx] = tile[tx][ty + j];
}

// ---------------- GEMM: C[M][N] = A[M][K] (bf16) x BT[N][K]^T (bf16) ----------------
#define BM 128
#define BN 128
#define BK 64

template <int OUTF32>
__global__ __launch_bounds__(256, 2) void gemm_bt_kernel(
    const ushort* __restrict__ A, const ushort* __restrict__ B,
    float* __restrict__ Cf, ushort* __restrict__ Cb,
    int M, int N, int K) {
  __shared__ __align__(16) ushort As[BM * BK];
  __shared__ __align__(16) ushort Bs[BN * BK];
  const int tid = threadIdx.x;
  const int wv = tid >> 6, ln = tid & 63;
  const int lr = ln & 15, lh = ln >> 4;
  const int bm = blockIdx.y, bn = blockIdx.x;
  const int wr = wv >> 1, wc = wv & 1;
  const int srow = wv * 8 + (ln >> 3);  // staging row within 32-row group
  const int scol = (ln & 7) * 8;        // staging col (elements)

  f32x4 acc[4][4] = {};

  for (int k0 = 0; k0 < K; k0 += BK) {
#pragma unroll
    for (int it = 0; it < 4; ++it)
      gload_lds16(&A[(size_t)(bm * BM + it * 32 + srow) * K + k0 + scol],
                  &As[(it * 32 + wv * 8) * BK]);
#pragma unroll
    for (int it = 0; it < 4; ++it)
      gload_lds16(&B[(size_t)(bn * BN + it * 32 + srow) * K + k0 + scol],
                  &Bs[(it * 32 + wv * 8) * BK]);
    __syncthreads();
#pragma unroll
    for (int kk = 0; kk < 2; ++kk) {
      bf16x8 af[4], bfv[4];
#pragma unroll
      for (int m = 0; m < 4; ++m)
        af[m] = *(const bf16x8*)&As[(wr * 64 + m * 16 + lr) * BK + kk * 32 + lh * 8];
#pragma unroll
      for (int n = 0; n < 4; ++n)
        bfv[n] = *(const bf16x8*)&Bs[(wc * 64 + n * 16 + lr) * BK + kk * 32 + lh * 8];
#pragma unroll
      for (int m = 0; m < 4; ++m)
#pragma unroll
        for (int n = 0; n < 4; ++n)
          acc[m][n] = mfma16(af[m], bfv[n], acc[m][n]);
    }
    __syncthreads();
  }

#pragma unroll
  for (int m = 0; m < 4; ++m) {
#pragma unroll
    for (int n = 0; n < 4; ++n) {
      const int row0 = bm * BM + wr * 64 + m * 16 + lh * 4;
      const int col = bn * BN + wc * 64 + n * 16 + lr;
#pragma unroll
      for (int r = 0; r < 4; ++r) {
        if (OUTF32)
          Cf[(size_t)(row0 + r) * N + col] = acc[m][n][r];
        else
          Cb[(size_t)(row0 + r) * N + col] = f2bfu(acc[m][n][r]);
      }
    }
  }
}

// ---------------- RoPE (interleaved pairs) on Q (32 heads) and K (16 heads) ----------------
__global__ __launch_bounds__(256) void rope_kernel(ushort* __restrict__ QKV,
                                                   const float* __restrict__ cosT,
                                                   const float* __restrict__ sinT) {
  const int t = blockIdx.x * 256 + threadIdx.x;  // 0..1535 = 48 heads * 32 pairs
  const int l = blockIdx.y;
  const int hh = t >> 5, j = t & 31;
  const int col = (hh < 32) ? (hh * 64 + 2 * j) : (2048 + (hh - 32) * 64 + 2 * j);
  ushort* p = &QKV[(size_t)l * D4 + col];
  const float tr = bfu2f(p[0]), ti = bfu2f(p[1]);
  const float c = cosT[l * 32 + j], s = sinT[l * 32 + j];
  p[0] = f2bfu(tr * c - ti * s);
  p[1] = f2bfu(tr * s + ti * c);
}

// ---------------- differential flash attention ----------------
// 512 blocks (one q-tile x head each, longest-first), 8 waves: 4 per softmax half.
// 2 blocks/CU co-resident (launch_bounds 512,4; 64 KB LDS x2 <= 160 KB).
// Double-buffered K, counted vmcnt keeps K(kt+1) in flight across the mid barrier.
// Diagonal-only causal masking; pre-scaled Q; defer-max (THR=8) skips O-rescale.
// LDS (ushort idx): Ks[2] [0,16384)  Vs [16384,24576)  P [24576,32768) = 64 KB.
__global__ __launch_bounds__(512, 4) void attn_kernel(const ushort* __restrict__ QKV,
                                                      const ushort* __restrict__ VT,
                                                      ushort* __restrict__ AO) {
  __shared__ __align__(16) ushort smem[32768];  // 64 KB
  const int b = blockIdx.x;
  const int qt = 31 - (b >> 4);  // longest q-tiles dispatch first
  const int h = b & 15, g = h >> 1;

  ushort* KsB = smem;           // 2 x [64 keys][128] swizzled
  ushort* Vs  = smem + 16384;   // [128 dv][64 keys] swizzled
  const int tid = threadIdx.x, wv = tid >> 6, ln = tid & 63;
  const int lr = ln & 15, lh = ln >> 4;
  const int half = wv >> 2, w4 = wv & 3;
  const int qbase = qt * 64 + w4 * 16;
  const int qh = 2 * h + half;
  ushort* Pw = smem + 24576 + wv * 1024;  // this wave's P [16 q][64 keys] swizzled

  // hoisted Q fragments for this wave's half, pre-scaled by 1/sqrt(64)
  bf16x8 a[2];
#pragma unroll
  for (int kk = 0; kk < 2; ++kk) {
    bf16x8 t = *(const bf16x8*)&QKV[(size_t)(qbase + lr) * D4 + qh * 64 + kk * 32 + lh * 8];
#pragma unroll
    for (int i = 0; i < 8; ++i) t[i] = (__bf16)((float)t[i] * 0.125f);
    a[kk] = t;
  }

  f32x4 o[8] = {};
  float m[4], lsum[4];
#pragma unroll
  for (int r = 0; r < 4; ++r) { m[r] = -INFINITY; lsum[r] = 0.f; }

  auto stageK = [&](ushort* buf, int krow0) {
#pragma unroll
    for (int it = 0; it < 2; ++it) {
      const int row = it * 32 + wv * 4 + lh;
      gload_lds16(&QKV[(size_t)(krow0 + row) * D4 + 2048 + g * 128 + (lr ^ (row & 7)) * 8],
                  &buf[(it * 32 + wv * 4) * 128]);
    }
  };
  auto stageV = [&](int krow0) {
#pragma unroll
    for (int it = 0; it < 2; ++it) {
      const int dv = it * 64 + wv * 8 + (ln >> 3);
      gload_lds16(&VT[(size_t)(g * 128 + dv) * 2048 + krow0 + ((ln & 7) ^ (dv & 7)) * 8],
                  &Vs[(it * 64 + wv * 8) * 64]);
    }
  };

  // one K/V tile step; DIAG = apply causal mask (only needed when kt == qt)
  auto step = [&](int kt, bool diag, int vm_outstanding) {
    const ushort* Kc = KsB + (kt & 1) * 8192;
    // ---- S = Q K^T (this wave's half only); Q pre-scaled ----
    f32x4 s[4] = {};
#pragma unroll
    for (int kk = 0; kk < 2; ++kk) {
#pragma unroll
      for (int n = 0; n < 4; ++n) {
        bf16x8 bb = *(const bf16x8*)&Kc[(n * 16 + lr) * 128 +
                                        ((half << 3) + (((kk << 2) + lh) ^ (lr & 7))) * 8];
        s[n] = mfma16(a[kk], bb, s[n]);
      }
    }

    // ---- per-row max (masked only on the diagonal tile) ----
    float sv[4][4];
    float mx[4];
#pragma unroll
    for (int r = 0; r < 4; ++r) {
      const int qrow = lh * 4 + r;
      float rmx = -INFINITY;
#pragma unroll
      for (int n = 0; n < 4; ++n) {
        float v = s[n][r];
        if (diag && (n * 16 + lr > w4 * 16 + qrow)) v = -INFINITY;
        sv[r][n] = v;
        rmx = fmaxf(rmx, v);
      }
#pragma unroll
      for (int off = 1; off < 16; off <<= 1) rmx = fmaxf(rmx, __shfl_xor(rmx, off));
      mx[r] = rmx;
    }

    // ---- defer-max: skip rescale when no row grew past THR=8 ----
    bool small = (mx[0] <= m[0] + 8.f) && (mx[1] <= m[1] + 8.f) &&
                 (mx[2] <= m[2] + 8.f) && (mx[3] <= m[3] + 8.f);
    if (__all(small)) {
#pragma unroll
      for (int r = 0; r < 4; ++r) {
        const int qrow = lh * 4 + r;
        float sum = 0.f;
#pragma unroll
        for (int n = 0; n < 4; ++n) {
          const float p = __expf(sv[r][n] - m[r]);
          sum += p;
          const int key = n * 16 + lr;
          Pw[qrow * 64 + (((key >> 3) ^ (qrow & 7)) << 3) + (key & 7)] = f2bfu(p);
        }
#pragma unroll
        for (int off = 1; off < 16; off <<= 1) sum += __shfl_xor(sum, off);
        lsum[r] += sum;
      }
    } else {
#pragma unroll
      for (int r = 0; r < 4; ++r) {
        const int qrow = lh * 4 + r;
        const float mnew = fmaxf(m[r], mx[r]);
        const float alpha = __expf(m[r] - mnew);
        float sum = 0.f;
#pragma unroll
        for (int n = 0; n < 4; ++n) {
          const float p = __expf(sv[r][n] - mnew);
          sum += p;
          const int key = n * 16 + lr;
          Pw[qrow * 64 + (((key >> 3) ^ (qrow & 7)) << 3) + (key & 7)] = f2bfu(p);
        }
#pragma unroll
        for (int off = 1; off < 16; off <<= 1) sum += __shfl_xor(sum, off);
        lsum[r] = lsum[r] * alpha + sum;
        m[r] = mnew;
#pragma unroll
        for (int nn = 0; nn < 8; ++nn) o[nn][r] *= alpha;
      }
    }

    // ---- wait own V(kt) (K(kt+1) may stay in flight), then cross-wave barrier ----
    if (vm_outstanding == 2) asm volatile("s_waitcnt vmcnt(2)" ::: "memory");
    else                     asm volatile("s_waitcnt vmcnt(0)" ::: "memory");
    __builtin_amdgcn_sched_barrier(0);
    __builtin_amdgcn_s_barrier();

    // ---- O += P V ----
#pragma unroll
    for (int kk = 0; kk < 2; ++kk) {
      bf16x8 pa = *(const bf16x8*)&Pw[lr * 64 + ((((kk << 2) + lh) ^ (lr & 7)) << 3)];
#pragma unroll
      for (int n = 0; n < 8; ++n) {
        const int dv = n * 16 + lr;
        bf16x8 bv = *(const bf16x8*)&Vs[dv * 64 + ((((kk << 2) + lh) ^ (lr & 7)) << 3)];
        o[n] = mfma16(pa, bv, o[n]);
      }
    }
  };

  // prologue: K tile 0
  stageK(KsB, 0);
  __syncthreads();

  for (int kt = 0; kt < qt; ++kt) {
    stageV(kt * 64);                         // V(kt): hidden under QK+softmax
    stageK(KsB + ((kt & 1) ^ 1) * 8192, kt * 64 + 64);  // K(kt+1): stays in flight
    step(kt, false, 2);
    __syncthreads();  // frees Vs + Ks[kt&1] for restage
  }
  // diagonal tile
  stageV(qt * 64);
  step(qt, true, 0);

  // ---- merge halves: out = O1/l1 - 0.2 * O2/l2 ----
  float* Os = (float*)smem;  // [64 q][128 dv] f32 = 32 KB, overlays Ks dbuf
  if (half == 1) {
#pragma unroll
    for (int n = 0; n < 8; ++n)
#pragma unroll
      for (int r = 0; r < 4; ++r)
        Os[(w4 * 16 + lh * 4 + r) * 128 + n * 16 + lr] = o[n][r] / lsum[r];
  }
  __syncthreads();
  if (half == 0) {
#pragma unroll
    for (int n = 0; n < 8; ++n) {
#pragma unroll
      for (int r = 0; r < 4; ++r) {
        const int grow = qbase + lh * 4 + r;
        const float v = o[n][r] / lsum[r] -
                        0.2f * Os[(w4 * 16 + lh * 4 + r) * 128 + n * 16 + lr];
        AO[(size_t)grow * 2048 + h * 128 + n * 16 + lr] = f2bfu(v);
      }
    }
  }
}

// ---------------------------------------------------------------------------
extern "C" void kernel_launch(void* const* d_in, const int* in_sizes, int n_in,
                              void* d_out, int out_size, void* d_ws, size_t ws_size,
                              hipStream_t stream) {
  (void)in_sizes; (void)n_in; (void)out_size; (void)ws_size;
  const float* x    = (const float*)d_in[0];
  const float* cosT = (const float*)d_in[1];
  const float* sinT = (const float*)d_in[2];
  const float* Wq   = (const float*)d_in[3];
  const float* Wk   = (const float*)d_in[4];
  const float* Wv   = (const float*)d_in[5];
  const float* Wo   = (const float*)d_in[6];
  float* out = (float*)d_out;

  ushort* ws = (ushort*)d_ws;
  // element offsets (2B each); total 28M elems = 56 MB
  ushort* xb   = ws;                 // [2048][2048] (dead after QKV GEMM)
  ushort* WT   = ws + 4194304;       // WqT [2048][2048]  (WqT|WkT|WvT contiguous)
  ushort* WkT  = ws + 8388608;       // [1024][2048]
  ushort* WvT  = ws + 10485760;      // [1024][2048]
  ushort* WoT  = ws + 12582912;      // [2048][2048]
  ushort* QKVb = ws + 16777216;      // [2048][4096] = Q|K|V bf16
  ushort* AOb  = ws + 25165824;      // [2048][2048] attn out bf16
  ushort* VT   = ws;                 // [1024][2048] V^T, overlays dead xb

  cvt_x_kernel<<<4096, 256, 0, stream>>>(x, xb);
  dim3 tb(32, 8);
  transpose_bf16_kernel<<<dim3(64, 64), tb, 0, stream>>>(Wq, WT, 2048, 2048);
  transpose_bf16_kernel<<<dim3(32, 64), tb, 0, stream>>>(Wk, WkT, 2048, 1024);
  transpose_bf16_kernel<<<dim3(32, 64), tb, 0, stream>>>(Wv, WvT, 2048, 1024);
  transpose_bf16_kernel<<<dim3(64, 64), tb, 0, stream>>>(Wo, WoT, 2048, 2048);

  // fused QKV projection: [2048][4096] = xb @ [WqT;WkT;WvT]^T
  gemm_bt_kernel<0><<<dim3(4096 / BN, 2048 / BM), 256, 0, stream>>>(
      xb, WT, nullptr, QKVb, 2048, 4096, 2048);

  rope_kernel<<<dim3(6, 2048), 256, 0, stream>>>(QKVb, cosT, sinT);
  vtrans_kernel<<<dim3(64, 32), tb, 0, stream>>>(QKVb, VT);  // xb now dead

  attn_kernel<<<512, 512, 0, stream>>>(QKVb, VT, AOb);

  // final projection -> f32 out
  gemm_bt_kernel<1><<<dim3(2048 / BN, 2048 / BM), 256, 0, stream>>>(
      AOb, WoT, out, nullptr, 2048, 2048, 2048);
}

// Round 6
// 310.008 us; speedup vs baseline: 1.1745x; 1.1745x over previous
//
#include <hip/hip_runtime.h>
#include <hip/hip_bf16.h>

// ---------------------------------------------------------------------------
// DiffAttention forward: x@Wq/Wk/Wv -> RoPE -> diff attn -> @Wo
// L=2048, DIM=2048, 16 heads x (2x64), KV 8 heads x (2x64), V dv=128, causal.
// lambda = 0.2, scale = 1/8.
// ---------------------------------------------------------------------------

typedef __bf16 bf16x8 __attribute__((ext_vector_type(8)));
typedef short  s16x8  __attribute__((ext_vector_type(8)));
typedef float  f32x4  __attribute__((ext_vector_type(4)));

#define D4 4096  // QKV buffer row width: [Q 2048 | K 1024 | V 1024]

__device__ __forceinline__ ushort f2bfu(float f) {
  __hip_bfloat16 h = __float2bfloat16(f);
  return __builtin_bit_cast(ushort, h);
}
__device__ __forceinline__ float bfu2f(ushort u) {
  return __bfloat162float(__builtin_bit_cast(__hip_bfloat16, u));
}
__device__ __forceinline__ void gload_lds16(const void* g, void* l) {
  __builtin_amdgcn_global_load_lds(
      (const __attribute__((address_space(1))) unsigned int*)g,
      (__attribute__((address_space(3))) unsigned int*)l, 16, 0, 0);
}
__device__ __forceinline__ f32x4 mfma16(bf16x8 a, bf16x8 b, f32x4 c) {
  return __builtin_amdgcn_mfma_f32_16x16x32_bf16(a, b, c, 0, 0, 0);
}

// ---------------- convert x (f32) -> bf16 ----------------
__global__ __launch_bounds__(256) void cvt_x_kernel(const float* __restrict__ x,
                                                    ushort* __restrict__ xb) {
  const int i = blockIdx.x * 256 + threadIdx.x;  // each handles 4 elems
  float4 v = ((const float4*)x)[i];
  ((ushort4*)xb)[i] = make_ushort4(f2bfu(v.x), f2bfu(v.y), f2bfu(v.z), f2bfu(v.w));
}

// ---------------- W [K][N] f32 -> WT [N][K] bf16 ----------------
__global__ __launch_bounds__(256) void transpose_bf16_kernel(const float* __restrict__ W,
                                                             ushort* __restrict__ WT,
                                                             int K, int N) {
  __shared__ float tile[32][33];
  const int bx = blockIdx.x, by = blockIdx.y;
  const int tx = threadIdx.x, ty = threadIdx.y;  // (32,8)
#pragma unroll
  for (int j = 0; j < 32; j += 8)
    tile[ty + j][tx] = W[(size_t)(by * 32 + ty + j) * N + bx * 32 + tx];
  __syncthreads();
#pragma unroll
  for (int j = 0; j < 32; j += 8)
    WT[(size_t)(bx * 32 + ty + j) * K + by * 32 + tx] = f2bfu(tile[tx][ty + j]);
}

// ---------------- V columns of QKV (bf16) -> VT[g*128+dv][l] (bf16) ----------------
__global__ __launch_bounds__(256) void vtrans_kernel(const ushort* __restrict__ QKV,
                                                     ushort* __restrict__ VT) {
  __shared__ ushort tile[32][34];
  const int bx = blockIdx.x, by = blockIdx.y;  // bx: l-tile (64), by: c-tile (32)
  const int tx = threadIdx.x, ty = threadIdx.y;  // (32,8)
#pragma unroll
  for (int j = 0; j < 32; j += 8)
    tile[ty + j][tx] = QKV[(size_t)(bx * 32 + ty + j) * D4 + 3072 + by * 32 + tx];
  __syncthreads();
#pragma unroll
  for (int j = 0; j < 32; j += 8)
    VT[(size_t)(by * 32 + ty + j) * 2048 + bx * 32 + tx] = tile[tx][ty + j];
}

// ---------------- GEMM: C[M][N] = A[M][K] (bf16) x BT[N][K]^T (bf16) ----------------
#define BM 128
#define BN 128
#define BK 64

template <int OUTF32>
__global__ __launch_bounds__(256, 2) void gemm_bt_kernel(
    const ushort* __restrict__ A, const ushort* __restrict__ B,
    float* __restrict__ Cf, ushort* __restrict__ Cb,
    int M, int N, int K) {
  __shared__ __align__(16) ushort As[BM * BK];
  __shared__ __align__(16) ushort Bs[BN * BK];
  const int tid = threadIdx.x;
  const int wv = tid >> 6, ln = tid & 63;
  const int lr = ln & 15, lh = ln >> 4;
  const int bm = blockIdx.y, bn = blockIdx.x;
  const int wr = wv >> 1, wc = wv & 1;
  const int srow = wv * 8 + (ln >> 3);  // staging row within 32-row group
  const int scol = (ln & 7) * 8;        // staging col (elements)

  f32x4 acc[4][4] = {};

  for (int k0 = 0; k0 < K; k0 += BK) {
#pragma unroll
    for (int it = 0; it < 4; ++it)
      gload_lds16(&A[(size_t)(bm * BM + it * 32 + srow) * K + k0 + scol],
                  &As[(it * 32 + wv * 8) * BK]);
#pragma unroll
    for (int it = 0; it < 4; ++it)
      gload_lds16(&B[(size_t)(bn * BN + it * 32 + srow) * K + k0 + scol],
                  &Bs[(it * 32 + wv * 8) * BK]);
    __syncthreads();
#pragma unroll
    for (int kk = 0; kk < 2; ++kk) {
      bf16x8 af[4], bfv[4];
#pragma unroll
      for (int m = 0; m < 4; ++m)
        af[m] = *(const bf16x8*)&As[(wr * 64 + m * 16 + lr) * BK + kk * 32 + lh * 8];
#pragma unroll
      for (int n = 0; n < 4; ++n)
        bfv[n] = *(const bf16x8*)&Bs[(wc * 64 + n * 16 + lr) * BK + kk * 32 + lh * 8];
#pragma unroll
      for (int m = 0; m < 4; ++m)
#pragma unroll
        for (int n = 0; n < 4; ++n)
          acc[m][n] = mfma16(af[m], bfv[n], acc[m][n]);
    }
    __syncthreads();
  }

#pragma unroll
  for (int m = 0; m < 4; ++m) {
#pragma unroll
    for (int n = 0; n < 4; ++n) {
      const int row0 = bm * BM + wr * 64 + m * 16 + lh * 4;
      const int col = bn * BN + wc * 64 + n * 16 + lr;
#pragma unroll
      for (int r = 0; r < 4; ++r) {
        if (OUTF32)
          Cf[(size_t)(row0 + r) * N + col] = acc[m][n][r];
        else
          Cb[(size_t)(row0 + r) * N + col] = f2bfu(acc[m][n][r]);
      }
    }
  }
}

// ---------------- RoPE (interleaved pairs) on Q (32 heads) and K (16 heads) ----------------
__global__ __launch_bounds__(256) void rope_kernel(ushort* __restrict__ QKV,
                                                   const float* __restrict__ cosT,
                                                   const float* __restrict__ sinT) {
  const int t = blockIdx.x * 256 + threadIdx.x;  // 0..1535 = 48 heads * 32 pairs
  const int l = blockIdx.y;
  const int hh = t >> 5, j = t & 31;
  const int col = (hh < 32) ? (hh * 64 + 2 * j) : (2048 + (hh - 32) * 64 + 2 * j);
  ushort* p = &QKV[(size_t)l * D4 + col];
  const float tr = bfu2f(p[0]), ti = bfu2f(p[1]);
  const float c = cosT[l * 32 + j], s = sinT[l * 32 + j];
  p[0] = f2bfu(tr * c - ti * s);
  p[1] = f2bfu(tr * s + ti * c);
}

// ---------------- differential flash attention ----------------
// 512 blocks (one q-tile x head each, longest-first), 8 waves: 4 per softmax half.
// 2 blocks/CU co-resident at runtime (VGPR<=128, LDS 64KBx2<=160KB);
// launch_bounds(512,2) — (512,4) forced VGPR=64 and spilled (R5: WRITE_SIZE 8->55MB).
// Double-buffered K, counted vmcnt keeps K(kt+1) in flight across the mid barrier.
// Diagonal-only causal masking; pre-scaled Q; defer-max (THR=8) skips O-rescale.
// LDS (ushort idx): Ks[2] [0,16384)  Vs [16384,24576)  P [24576,32768) = 64 KB.
__global__ __launch_bounds__(512, 2) void attn_kernel(const ushort* __restrict__ QKV,
                                                      const ushort* __restrict__ VT,
                                                      ushort* __restrict__ AO) {
  __shared__ __align__(16) ushort smem[32768];  // 64 KB
  const int b = blockIdx.x;
  const int qt = 31 - (b >> 4);  // longest q-tiles dispatch first
  const int h = b & 15, g = h >> 1;

  ushort* KsB = smem;           // 2 x [64 keys][128] swizzled
  ushort* Vs  = smem + 16384;   // [128 dv][64 keys] swizzled
  const int tid = threadIdx.x, wv = tid >> 6, ln = tid & 63;
  const int lr = ln & 15, lh = ln >> 4;
  const int half = wv >> 2, w4 = wv & 3;
  const int qbase = qt * 64 + w4 * 16;
  const int qh = 2 * h + half;
  ushort* Pw = smem + 24576 + wv * 1024;  // this wave's P [16 q][64 keys] swizzled

  // hoisted Q fragments for this wave's half, pre-scaled by 1/sqrt(64)
  bf16x8 a[2];
#pragma unroll
  for (int kk = 0; kk < 2; ++kk) {
    bf16x8 t = *(const bf16x8*)&QKV[(size_t)(qbase + lr) * D4 + qh * 64 + kk * 32 + lh * 8];
#pragma unroll
    for (int i = 0; i < 8; ++i) t[i] = (__bf16)((float)t[i] * 0.125f);
    a[kk] = t;
  }

  f32x4 o[8] = {};
  float m[4], lsum[4];
#pragma unroll
  for (int r = 0; r < 4; ++r) { m[r] = -INFINITY; lsum[r] = 0.f; }

  auto stageK = [&](ushort* buf, int krow0) {
#pragma unroll
    for (int it = 0; it < 2; ++it) {
      const int row = it * 32 + wv * 4 + lh;
      gload_lds16(&QKV[(size_t)(krow0 + row) * D4 + 2048 + g * 128 + (lr ^ (row & 7)) * 8],
                  &buf[(it * 32 + wv * 4) * 128]);
    }
  };
  auto stageV = [&](int krow0) {
#pragma unroll
    for (int it = 0; it < 2; ++it) {
      const int dv = it * 64 + wv * 8 + (ln >> 3);
      gload_lds16(&VT[(size_t)(g * 128 + dv) * 2048 + krow0 + ((ln & 7) ^ (dv & 7)) * 8],
                  &Vs[(it * 64 + wv * 8) * 64]);
    }
  };

  // one K/V tile step; diag = apply causal mask (only needed when kt == qt)
  auto step = [&](int kt, bool diag, int vm_outstanding) {
    const ushort* Kc = KsB + (kt & 1) * 8192;
    // ---- S = Q K^T (this wave's half only); Q pre-scaled ----
    f32x4 s[4] = {};
#pragma unroll
    for (int kk = 0; kk < 2; ++kk) {
#pragma unroll
      for (int n = 0; n < 4; ++n) {
        bf16x8 bb = *(const bf16x8*)&Kc[(n * 16 + lr) * 128 +
                                        ((half << 3) + (((kk << 2) + lh) ^ (lr & 7))) * 8];
        s[n] = mfma16(a[kk], bb, s[n]);
      }
    }

    // ---- per-row max (masked only on the diagonal tile) ----
    float sv[4][4];
    float mx[4];
#pragma unroll
    for (int r = 0; r < 4; ++r) {
      const int qrow = lh * 4 + r;
      float rmx = -INFINITY;
#pragma unroll
      for (int n = 0; n < 4; ++n) {
        float v = s[n][r];
        if (diag && (n * 16 + lr > w4 * 16 + qrow)) v = -INFINITY;
        sv[r][n] = v;
        rmx = fmaxf(rmx, v);
      }
#pragma unroll
      for (int off = 1; off < 16; off <<= 1) rmx = fmaxf(rmx, __shfl_xor(rmx, off));
      mx[r] = rmx;
    }

    // ---- defer-max: skip rescale when no row grew past THR=8 ----
    bool small = (mx[0] <= m[0] + 8.f) && (mx[1] <= m[1] + 8.f) &&
                 (mx[2] <= m[2] + 8.f) && (mx[3] <= m[3] + 8.f);
    if (__all(small)) {
#pragma unroll
      for (int r = 0; r < 4; ++r) {
        const int qrow = lh * 4 + r;
        float sum = 0.f;
#pragma unroll
        for (int n = 0; n < 4; ++n) {
          const float p = __expf(sv[r][n] - m[r]);
          sum += p;
          const int key = n * 16 + lr;
          Pw[qrow * 64 + (((key >> 3) ^ (qrow & 7)) << 3) + (key & 7)] = f2bfu(p);
        }
#pragma unroll
        for (int off = 1; off < 16; off <<= 1) sum += __shfl_xor(sum, off);
        lsum[r] += sum;
      }
    } else {
#pragma unroll
      for (int r = 0; r < 4; ++r) {
        const int qrow = lh * 4 + r;
        const float mnew = fmaxf(m[r], mx[r]);
        const float alpha = __expf(m[r] - mnew);
        float sum = 0.f;
#pragma unroll
        for (int n = 0; n < 4; ++n) {
          const float p = __expf(sv[r][n] - mnew);
          sum += p;
          const int key = n * 16 + lr;
          Pw[qrow * 64 + (((key >> 3) ^ (qrow & 7)) << 3) + (key & 7)] = f2bfu(p);
        }
#pragma unroll
        for (int off = 1; off < 16; off <<= 1) sum += __shfl_xor(sum, off);
        lsum[r] = lsum[r] * alpha + sum;
        m[r] = mnew;
#pragma unroll
        for (int nn = 0; nn < 8; ++nn) o[nn][r] *= alpha;
      }
    }

    // ---- wait own V(kt) (K(kt+1) may stay in flight), then cross-wave barrier ----
    if (vm_outstanding == 2) asm volatile("s_waitcnt vmcnt(2)" ::: "memory");
    else                     asm volatile("s_waitcnt vmcnt(0)" ::: "memory");
    __builtin_amdgcn_sched_barrier(0);
    __builtin_amdgcn_s_barrier();

    // ---- O += P V ----
#pragma unroll
    for (int kk = 0; kk < 2; ++kk) {
      bf16x8 pa = *(const bf16x8*)&Pw[lr * 64 + ((((kk << 2) + lh) ^ (lr & 7)) << 3)];
#pragma unroll
      for (int n = 0; n < 8; ++n) {
        const int dv = n * 16 + lr;
        bf16x8 bv = *(const bf16x8*)&Vs[dv * 64 + ((((kk << 2) + lh) ^ (lr & 7)) << 3)];
        o[n] = mfma16(pa, bv, o[n]);
      }
    }
  };

  // prologue: K tile 0
  stageK(KsB, 0);
  __syncthreads();

  for (int kt = 0; kt < qt; ++kt) {
    stageV(kt * 64);                         // V(kt): hidden under QK+softmax
    stageK(KsB + ((kt & 1) ^ 1) * 8192, kt * 64 + 64);  // K(kt+1): stays in flight
    step(kt, false, 2);
    __syncthreads();  // frees Vs + Ks[kt&1] for restage
  }
  // diagonal tile
  stageV(qt * 64);
  step(qt, true, 0);

  // ---- merge halves: out = O1/l1 - 0.2 * O2/l2 ----
  float* Os = (float*)smem;  // [64 q][128 dv] f32 = 32 KB, overlays Ks dbuf
  if (half == 1) {
#pragma unroll
    for (int n = 0; n < 8; ++n)
#pragma unroll
      for (int r = 0; r < 4; ++r)
        Os[(w4 * 16 + lh * 4 + r) * 128 + n * 16 + lr] = o[n][r] / lsum[r];
  }
  __syncthreads();
  if (half == 0) {
#pragma unroll
    for (int n = 0; n < 8; ++n) {
#pragma unroll
      for (int r = 0; r < 4; ++r) {
        const int grow = qbase + lh * 4 + r;
        const float v = o[n][r] / lsum[r] -
                        0.2f * Os[(w4 * 16 + lh * 4 + r) * 128 + n * 16 + lr];
        AO[(size_t)grow * 2048 + h * 128 + n * 16 + lr] = f2bfu(v);
      }
    }
  }
}

// ---------------------------------------------------------------------------
extern "C" void kernel_launch(void* const* d_in, const int* in_sizes, int n_in,
                              void* d_out, int out_size, void* d_ws, size_t ws_size,
                              hipStream_t stream) {
  (void)in_sizes; (void)n_in; (void)out_size; (void)ws_size;
  const float* x    = (const float*)d_in[0];
  const float* cosT = (const float*)d_in[1];
  const float* sinT = (const float*)d_in[2];
  const float* Wq   = (const float*)d_in[3];
  const float* Wk   = (const float*)d_in[4];
  const float* Wv   = (const float*)d_in[5];
  const float* Wo   = (const float*)d_in[6];
  float* out = (float*)d_out;

  ushort* ws = (ushort*)d_ws;
  // element offsets (2B each); total 28M elems = 56 MB
  ushort* xb   = ws;                 // [2048][2048] (dead after QKV GEMM)
  ushort* WT   = ws + 4194304;       // WqT [2048][2048]  (WqT|WkT|WvT contiguous)
  ushort* WkT  = ws + 8388608;       // [1024][2048]
  ushort* WvT  = ws + 10485760;      // [1024][2048]
  ushort* WoT  = ws + 12582912;      // [2048][2048]
  ushort* QKVb = ws + 16777216;      // [2048][4096] = Q|K|V bf16
  ushort* AOb  = ws + 25165824;      // [2048][2048] attn out bf16
  ushort* VT   = ws;                 // [1024][2048] V^T, overlays dead xb

  cvt_x_kernel<<<4096, 256, 0, stream>>>(x, xb);
  dim3 tb(32, 8);
  transpose_bf16_kernel<<<dim3(64, 64), tb, 0, stream>>>(Wq, WT, 2048, 2048);
  transpose_bf16_kernel<<<dim3(32, 64), tb, 0, stream>>>(Wk, WkT, 2048, 1024);
  transpose_bf16_kernel<<<dim3(32, 64), tb, 0, stream>>>(Wv, WvT, 2048, 1024);
  transpose_bf16_kernel<<<dim3(64, 64), tb, 0, stream>>>(Wo, WoT, 2048, 2048);

  // fused QKV projection: [2048][4096] = xb @ [WqT;WkT;WvT]^T
  gemm_bt_kernel<0><<<dim3(4096 / BN, 2048 / BM), 256, 0, stream>>>(
      xb, WT, nullptr, QKVb, 2048, 4096, 2048);

  rope_kernel<<<dim3(6, 2048), 256, 0, stream>>>(QKVb, cosT, sinT);
  vtrans_kernel<<<dim3(64, 32), tb, 0, stream>>>(QKVb, VT);  // xb now dead

  attn_kernel<<<512, 512, 0, stream>>>(QKVb, VT, AOb);

  // final projection -> f32 out
  gemm_bt_kernel<1><<<dim3(2048 / BN, 2048 / BM), 256, 0, stream>>>(
      AOb, WoT, out, nullptr, 2048, 2048, 2048);
}